// Round 1
// baseline (14025.537 us; speedup 1.0000x reference)
//
#include <hip/hip_runtime.h>
#include <hip/hip_cooperative_groups.h>

namespace cg = cooperative_groups;

// ---------------------------------------------------------------------------
// LSTM (L=4, B=64, T=256, H=D=1024, O=512).
// Round 3: single persistent cooperative kernel (grid.sync per diagonal),
// 512-thread WGs with K-split-8 (2 waves/SIMD), depth-2 prefetch, and
// MFMA-fragment-order packed W/x/h so every global fragment load is one
// contiguous 1KB wave transaction.
// Packed layout for a [R x K] bf16 operand: [R/16][K/8][R%16][8].
// Gate-interleaved rows: packed row n = gate (n&3) of unit (n>>2).
// ---------------------------------------------------------------------------

typedef short           bf16x8 __attribute__((ext_vector_type(8)));
typedef unsigned short  u16x8  __attribute__((ext_vector_type(8)));
typedef float           f32x4  __attribute__((ext_vector_type(4)));

static constexpr int kB  = 64;
static constexpr int kT  = 256;
static constexpr int kH  = 1024;
static constexpr int kL  = 4;
static constexpr int kNG = 4096;       // 4*H

static constexpr int    kABlk   = 65536;    // one A half: [4][128][16][8] = 64x1024
static constexpr size_t kWLayer = 8388608;  // [256][256][16][8] = 4096x2048

// ws layout (bytes)
static constexpr size_t OFF_W    = 0;           // bf16 Wp    67,108,864
static constexpr size_t OFF_BIAS = 67108864;    // f32 bias       65,536
static constexpr size_t OFF_XB   = 67174400;    // bf16 xp    33,554,432
static constexpr size_t OFF_H    = 100728832;   // bf16 hp[2][L][64x1024] 1 MB
static constexpr size_t OFF_C    = 101777408;   // f32  cp[L][64x1024]    1 MB

static __device__ __forceinline__ unsigned short f2bf(float f) {
  unsigned int u = __float_as_uint(f);
  u += 0x7fffu + ((u >> 16) & 1u);  // RNE
  return (unsigned short)(u >> 16);
}
static __device__ __forceinline__ float bf2f(unsigned short s) {
  return __uint_as_float(((unsigned int)s) << 16);
}
static __device__ __forceinline__ float sigm_(float x) {
  return 1.0f / (1.0f + __expf(-x));
}
static __device__ __forceinline__ float tanh_(float x) {
  return 1.0f - 2.0f / (__expf(2.0f * x) + 1.0f);
}

// Pack weights: Wp[l][r16][k8][l15][8], row n=r16*16+l15 (gate-interleaved),
// source row r=(n&3)*1024+(n>>2); k = k8*8 (<1024 -> Wih, else Whh).
__global__ __launch_bounds__(256) void prepack_w(const float* __restrict__ Wih,
                                                 const float* __restrict__ Whh,
                                                 unsigned short* __restrict__ Wp) {
  unsigned int e8 = blockIdx.x * 256 + threadIdx.x;  // < 4,194,304 (exact)
  const int l15 = e8 & 15;
  const int k8  = (e8 >> 4) & 255;
  const int r16 = (e8 >> 12) & 255;
  const int l   = e8 >> 20;
  const int n   = r16 * 16 + l15;
  const int r   = (n & 3) * 1024 + (n >> 2);
  const int k   = k8 * 8;
  const float* src = (k < 1024)
      ? (Wih + ((size_t)l * kNG + r) * 1024 + k)
      : (Whh + ((size_t)l * kNG + r) * 1024 + (k - 1024));
  float4 f0 = *(const float4*)(src);
  float4 f1 = *(const float4*)(src + 4);
  u16x8 v;
  v[0] = f2bf(f0.x); v[1] = f2bf(f0.y); v[2] = f2bf(f0.z); v[3] = f2bf(f0.w);
  v[4] = f2bf(f1.x); v[5] = f2bf(f1.y); v[6] = f2bf(f1.z); v[7] = f2bf(f1.w);
  *(u16x8*)(Wp + (size_t)e8 * 8) = v;
}

__global__ __launch_bounds__(256) void prepack_bias(const float* __restrict__ bih,
                                                    const float* __restrict__ bhh,
                                                    float* __restrict__ bias) {
  int e = blockIdx.x * 256 + threadIdx.x;  // 16384 exact
  int l = e >> 12, n = e & 4095;
  int r = (n & 3) * 1024 + (n >> 2);
  bias[e] = bih[l * kNG + r] + bhh[l * kNG + r];
}

// Pack x: xp[t][m16][k8][l15][8], batch m=m16*16+l15.
__global__ __launch_bounds__(256) void prepack_x(const float* __restrict__ x,
                                                 unsigned short* __restrict__ xp) {
  unsigned int e8 = blockIdx.x * 256 + threadIdx.x;  // < 2,097,152 (exact)
  const int l15 = e8 & 15;
  const int k8  = (e8 >> 4) & 127;
  const int m16 = (e8 >> 11) & 3;
  const int t   = e8 >> 13;
  const int mm  = m16 * 16 + l15;
  const float* src = x + ((size_t)mm * kT + t) * kH + k8 * 8;
  float4 f0 = *(const float4*)(src);
  float4 f1 = *(const float4*)(src + 4);
  u16x8 v;
  v[0] = f2bf(f0.x); v[1] = f2bf(f0.y); v[2] = f2bf(f0.z); v[3] = f2bf(f0.w);
  v[4] = f2bf(f1.x); v[5] = f2bf(f1.y); v[6] = f2bf(f1.z); v[7] = f2bf(f1.w);
  *(u16x8*)(xp + (size_t)e8 * 8) = v;
}

// Persistent diagonal-wavefront kernel. 256 WGs (l = bid>>6, slab = bid&63),
// 512 threads = 8 waves, K-split-8 (waves 0-3 input half, 4-7 recurrent half).
__global__ __launch_bounds__(512, 2) void lstm_persist(
    const unsigned short* __restrict__ Wp, const float* __restrict__ bias,
    const unsigned short* __restrict__ xp, unsigned short* __restrict__ hp,
    float* __restrict__ cp) {
  cg::grid_group grid = cg::this_grid();

  const int l    = blockIdx.x >> 6;
  const int slab = blockIdx.x & 63;
  const int tid  = threadIdx.x;
  const int lane = tid & 63;
  const int w    = tid >> 6;       // 0..7: K range [w*256, w*256+256)
  const int quad = lane >> 4;
  const int l15  = lane & 15;
  const int half = w >> 2;         // 0: input half, 1: recurrent half
  const int wloc = w & 3;

  __shared__ float part[8][64][68];  // 139,264 B (fits 160 KB @ 1 WG/CU)

  // Invariant B lane pointers: row = slab*64 + i*16 + l15, k8 = w*32 + quad.
  const unsigned short* pB[4];
#pragma unroll
  for (int i = 0; i < 4; ++i)
    pB[i] = Wp + ((((size_t)(l * 256 + slab * 4 + i)) * 256 +
                   (size_t)(w * 32 + quad)) * 16 + l15) * 8;

  // Invariant A lane offsets within a packed half-buffer.
  size_t aoff[4];
#pragma unroll
  for (int i = 0; i < 4; ++i)
    aoff[i] = (((size_t)(i * 128 + wloc * 32 + quad)) * 16 + l15) * 8;

  for (int d = 0; d < kT + kL - 1; ++d) {
    const int t = d - l;
    if (t >= 0 && t < kT) {
      const unsigned short* srcA;
      if (half == 0) {
        srcA = (l == 0) ? (xp + (size_t)t * kABlk)
                        : (hp + ((size_t)((t & 1) * kL + (l - 1))) * kABlk);
      } else {
        srcA = hp + ((size_t)(((t + 1) & 1) * kL + l)) * kABlk;
      }

      f32x4 acc[4][4] = {};
      bf16x8 Af[3][4], Bw[3][4];
      // depth-2 prefetch prologue (kc stride = 512 elements = 1 KB)
#pragma unroll
      for (int i = 0; i < 4; ++i) {
        Af[0][i] = *(const bf16x8*)(srcA + aoff[i]);
        Bw[0][i] = *(const bf16x8*)(pB[i]);
      }
#pragma unroll
      for (int i = 0; i < 4; ++i) {
        Af[1][i] = *(const bf16x8*)(srcA + aoff[i] + 512);
        Bw[1][i] = *(const bf16x8*)(pB[i] + 512);
      }
#pragma unroll
      for (int kc = 0; kc < 8; ++kc) {
        const int cur = kc % 3;
        const int nxt = (kc + 2) % 3;
        if (kc < 6) {
#pragma unroll
          for (int i = 0; i < 4; ++i) {
            Af[nxt][i] = *(const bf16x8*)(srcA + aoff[i] + (size_t)(kc + 2) * 512);
            Bw[nxt][i] = *(const bf16x8*)(pB[i] + (size_t)(kc + 2) * 512);
          }
        }
#pragma unroll
        for (int mt = 0; mt < 4; ++mt)
#pragma unroll
          for (int nt = 0; nt < 4; ++nt)
            acc[mt][nt] = __builtin_amdgcn_mfma_f32_16x16x32_bf16(
                Af[cur][mt], Bw[cur][nt], acc[mt][nt], 0, 0, 0);
      }

      // ---- write per-wave partials (stride 68: 8-way = LDS BW floor) ----
      {
        float* p = &part[w][0][0];
#pragma unroll
        for (int mt = 0; mt < 4; ++mt)
#pragma unroll
          for (int nt = 0; nt < 4; ++nt)
#pragma unroll
            for (int r = 0; r < 4; ++r)
              p[(mt * 16 + quad * 4 + r) * 68 + nt * 16 + l15] = acc[mt][nt][r];
      }
      __syncthreads();

      // ---- epilogue: thread -> batch m=lane, units u0=slab*16+2w, u0+1 ----
      {
        f32x4 s0 = {}, s1 = {};
#pragma unroll
        for (int p8 = 0; p8 < 8; ++p8) {
          s0 += *(const f32x4*)&part[p8][lane][8 * w];
          s1 += *(const f32x4*)&part[p8][lane][8 * w + 4];
        }
        const float* bb = bias + (size_t)l * kNG + slab * 64 + 8 * w;
        s0 += *(const f32x4*)bb;
        s1 += *(const f32x4*)(bb + 4);
        const int u0 = slab * 16 + 2 * w;
        const size_t off = ((size_t)((lane >> 4) * 128 + (u0 >> 3))) * 128 +
                           (lane & 15) * 8 + (u0 & 7);
        float* cpl = cp + (size_t)l * kABlk + off;
        float c0 = cpl[0], c1 = cpl[1];
        float gi0 = sigm_(s0[0]), gf0 = sigm_(s0[1]);
        float gg0 = tanh_(s0[2]), go0 = sigm_(s0[3]);
        float gi1 = sigm_(s1[0]), gf1 = sigm_(s1[1]);
        float gg1 = tanh_(s1[2]), go1 = sigm_(s1[3]);
        float cn0 = gf0 * c0 + gi0 * gg0;
        float cn1 = gf1 * c1 + gi1 * gg1;
        cpl[0] = cn0;
        cpl[1] = cn1;
        unsigned int hv = (unsigned int)f2bf(go0 * tanh_(cn0)) |
                          ((unsigned int)f2bf(go1 * tanh_(cn1)) << 16);
        *(unsigned int*)(hp + ((size_t)((t & 1) * kL + l)) * kABlk + off) = hv;
      }
    }
    grid.sync();
  }
}

// Final FC: out[64,512] = h[L-1, t=255] @ W_fc^T + b_fc (h3 in packed layout).
__global__ __launch_bounds__(256) void lstm_fc(const unsigned short* __restrict__ h3,
                                               const float* __restrict__ Wfc,
                                               const float* __restrict__ bfc,
                                               float* __restrict__ out) {
  int gt = blockIdx.x * 256 + threadIdx.x;  // 32768 exact
  int b = gt >> 9, o = gt & 511;
  const unsigned short* hr = h3 + (size_t)(b >> 4) * 16384 + (b & 15) * 8;
  const float* wr = Wfc + (size_t)o * kH;
  float acc = bfc[o];
#pragma unroll 4
  for (int k8 = 0; k8 < 128; ++k8) {
    u16x8 hv = *(const u16x8*)(hr + (size_t)k8 * 128);
    float4 w0 = *(const float4*)(wr + k8 * 8);
    float4 w1 = *(const float4*)(wr + k8 * 8 + 4);
    acc += bf2f(hv[0]) * w0.x + bf2f(hv[1]) * w0.y + bf2f(hv[2]) * w0.z +
           bf2f(hv[3]) * w0.w + bf2f(hv[4]) * w1.x + bf2f(hv[5]) * w1.y +
           bf2f(hv[6]) * w1.z + bf2f(hv[7]) * w1.w;
  }
  out[gt] = acc;
}

extern "C" void kernel_launch(void* const* d_in, const int* in_sizes, int n_in,
                              void* d_out, int out_size, void* d_ws, size_t ws_size,
                              hipStream_t stream) {
  (void)in_sizes; (void)n_in; (void)out_size; (void)ws_size;
  const float* x   = (const float*)d_in[0];
  const float* Wih = (const float*)d_in[1];
  const float* Whh = (const float*)d_in[2];
  const float* bih = (const float*)d_in[3];
  const float* bhh = (const float*)d_in[4];
  const float* Wfc = (const float*)d_in[5];
  const float* bfc = (const float*)d_in[6];
  float* out = (float*)d_out;

  char* ws = (char*)d_ws;
  unsigned short* Wp   = (unsigned short*)(ws + OFF_W);
  float*          bias = (float*)(ws + OFF_BIAS);
  unsigned short* xp   = (unsigned short*)(ws + OFF_XB);
  unsigned short* hpp  = (unsigned short*)(ws + OFF_H);
  float*          cpp  = (float*)(ws + OFF_C);

  prepack_w<<<16384, 256, 0, stream>>>(Wih, Whh, Wp);
  prepack_bias<<<64, 256, 0, stream>>>(bih, bhh, bias);
  prepack_x<<<8192, 256, 0, stream>>>(x, xp);
  hipMemsetAsync(ws + OFF_H, 0, 2097152, stream);  // hp (both slots) + cp

  void* args[5] = {(void*)&Wp, (void*)&bias, (void*)&xp, (void*)&hpp, (void*)&cpp};
  hipLaunchCooperativeKernel((void*)lstm_persist, dim3(256), dim3(512), args, 0,
                             stream);

  // h[layer 3] at t=255 -> slot 1: offset (1*4+3)*kABlk
  lstm_fc<<<128, 256, 0, stream>>>(hpp + (size_t)7 * kABlk, Wfc, bfc, out);
}

// Round 2
// 9859.910 us; speedup vs baseline: 1.4225x; 1.4225x over previous
//
#include <hip/hip_runtime.h>
#include <hip/hip_cooperative_groups.h>

namespace cg = cooperative_groups;

// ---------------------------------------------------------------------------
// LSTM (L=4, B=64, T=256, H=D=1024, O=512).
// Round 4: persistent cooperative kernel with WEIGHTS PINNED IN VGPRS.
// grid.sync()'s device-scope acquire invalidates per-XCD L2 every diagonal,
// so any cached weight line is lost (R3 counters: 9.15 GB FETCH = 35 MB/step
// = weights refetched every step at 725 GB/s latency-bound => 54 us/step).
// Fix: each wave's 64x256 B-tile (32 bf16x8 frags = 128 VGPRs) is loaded ONCE
// and lives in registers across all 259 diagonals. Cell state c (2 floats per
// thread, thread->unit mapping constant) and bias (8 floats) also in regs.
// Per-step global traffic is now only A fragments (x/h) + 512 KB h writes.
// Packed layout for a [R x K] bf16 operand: [R/16][K/8][R%16][8].
// Gate-interleaved rows: packed row n = gate (n&3) of unit (n>>2).
// ---------------------------------------------------------------------------

typedef short           bf16x8 __attribute__((ext_vector_type(8)));
typedef unsigned short  u16x8  __attribute__((ext_vector_type(8)));
typedef float           f32x4  __attribute__((ext_vector_type(4)));

static constexpr int kB  = 64;
static constexpr int kT  = 256;
static constexpr int kH  = 1024;
static constexpr int kL  = 4;
static constexpr int kNG = 4096;       // 4*H

static constexpr int kABlk = 65536;    // one A half: [4][128][16][8] = 64x1024

// ws layout (bytes)
static constexpr size_t OFF_W    = 0;           // bf16 Wp    67,108,864
static constexpr size_t OFF_BIAS = 67108864;    // f32 bias       65,536
static constexpr size_t OFF_XB   = 67174400;    // bf16 xp    33,554,432
static constexpr size_t OFF_H    = 100728832;   // bf16 hp[2][L][64x1024] 1 MB

static __device__ __forceinline__ unsigned short f2bf(float f) {
  unsigned int u = __float_as_uint(f);
  u += 0x7fffu + ((u >> 16) & 1u);  // RNE
  return (unsigned short)(u >> 16);
}
static __device__ __forceinline__ float bf2f(unsigned short s) {
  return __uint_as_float(((unsigned int)s) << 16);
}
static __device__ __forceinline__ float sigm_(float x) {
  return 1.0f / (1.0f + __expf(-x));
}
static __device__ __forceinline__ float tanh_(float x) {
  return 1.0f - 2.0f / (__expf(2.0f * x) + 1.0f);
}

// Pack weights: Wp[l][r16][k8][l15][8], row n=r16*16+l15 (gate-interleaved),
// source row r=(n&3)*1024+(n>>2); k = k8*8 (<1024 -> Wih, else Whh).
__global__ __launch_bounds__(256) void prepack_w(const float* __restrict__ Wih,
                                                 const float* __restrict__ Whh,
                                                 unsigned short* __restrict__ Wp) {
  unsigned int e8 = blockIdx.x * 256 + threadIdx.x;  // < 4,194,304 (exact)
  const int l15 = e8 & 15;
  const int k8  = (e8 >> 4) & 255;
  const int r16 = (e8 >> 12) & 255;
  const int l   = e8 >> 20;
  const int n   = r16 * 16 + l15;
  const int r   = (n & 3) * 1024 + (n >> 2);
  const int k   = k8 * 8;
  const float* src = (k < 1024)
      ? (Wih + ((size_t)l * kNG + r) * 1024 + k)
      : (Whh + ((size_t)l * kNG + r) * 1024 + (k - 1024));
  float4 f0 = *(const float4*)(src);
  float4 f1 = *(const float4*)(src + 4);
  u16x8 v;
  v[0] = f2bf(f0.x); v[1] = f2bf(f0.y); v[2] = f2bf(f0.z); v[3] = f2bf(f0.w);
  v[4] = f2bf(f1.x); v[5] = f2bf(f1.y); v[6] = f2bf(f1.z); v[7] = f2bf(f1.w);
  *(u16x8*)(Wp + (size_t)e8 * 8) = v;
}

__global__ __launch_bounds__(256) void prepack_bias(const float* __restrict__ bih,
                                                    const float* __restrict__ bhh,
                                                    float* __restrict__ bias) {
  int e = blockIdx.x * 256 + threadIdx.x;  // 16384 exact
  int l = e >> 12, n = e & 4095;
  int r = (n & 3) * 1024 + (n >> 2);
  bias[e] = bih[l * kNG + r] + bhh[l * kNG + r];
}

// Pack x: xp[t][m16][k8][l15][8], batch m=m16*16+l15.
__global__ __launch_bounds__(256) void prepack_x(const float* __restrict__ x,
                                                 unsigned short* __restrict__ xp) {
  unsigned int e8 = blockIdx.x * 256 + threadIdx.x;  // < 2,097,152 (exact)
  const int l15 = e8 & 15;
  const int k8  = (e8 >> 4) & 127;
  const int m16 = (e8 >> 11) & 3;
  const int t   = e8 >> 13;
  const int mm  = m16 * 16 + l15;
  const float* src = x + ((size_t)mm * kT + t) * kH + k8 * 8;
  float4 f0 = *(const float4*)(src);
  float4 f1 = *(const float4*)(src + 4);
  u16x8 v;
  v[0] = f2bf(f0.x); v[1] = f2bf(f0.y); v[2] = f2bf(f0.z); v[3] = f2bf(f0.w);
  v[4] = f2bf(f1.x); v[5] = f2bf(f1.y); v[6] = f2bf(f1.z); v[7] = f2bf(f1.w);
  *(u16x8*)(xp + (size_t)e8 * 8) = v;
}

// Persistent diagonal-wavefront kernel. 256 WGs (l = bid>>6, slab = bid&63),
// 512 threads = 8 waves, K-split-8 (waves 0-3 input half, 4-7 recurrent half).
// Weights resident in VGPRs; c resident in VGPRs; bias resident in VGPRs.
__global__ __launch_bounds__(512, 2) void lstm_persist(
    const unsigned short* __restrict__ Wp, const float* __restrict__ bias,
    const unsigned short* __restrict__ xp, unsigned short* __restrict__ hp) {
  cg::grid_group grid = cg::this_grid();

  const int l    = blockIdx.x >> 6;
  const int slab = blockIdx.x & 63;
  const int tid  = threadIdx.x;
  const int lane = tid & 63;
  const int w    = tid >> 6;       // 0..7: K range [w*256, w*256+256)
  const int quad = lane >> 4;
  const int l15  = lane & 15;
  const int half = w >> 2;         // 0: input half, 1: recurrent half
  const int wloc = w & 3;

  __shared__ float part[8][64][68];  // 139,264 B (fits 160 KB @ 1 WG/CU)

  // ---- one-time: load this wave's B tile (64 rows x 256 k) into VGPRs ----
  bf16x8 Bw[8][4];  // [kc][nt] : 32 frags = 128 VGPRs, live whole kernel
  {
#pragma unroll
    for (int i = 0; i < 4; ++i) {
      const unsigned short* pb =
          Wp + ((((size_t)(l * 256 + slab * 4 + i)) * 256 +
                 (size_t)(w * 32 + quad)) * 16 + l15) * 8;
#pragma unroll
      for (int kc = 0; kc < 8; ++kc)
        Bw[kc][i] = *(const bf16x8*)(pb + (size_t)kc * 512);
    }
  }

  // ---- one-time: bias for this thread's 2 units (u0 = slab*16+2w, +1) ----
  const int u0 = slab * 16 + 2 * w;
  f32x4 bb0, bb1;
  {
    const float* bb = bias + (size_t)l * kNG + slab * 64 + 8 * w;
    bb0 = *(const f32x4*)bb;
    bb1 = *(const f32x4*)(bb + 4);
  }
  // cell state in registers (thread->unit mapping constant across steps)
  float c0 = 0.0f, c1 = 0.0f;

  // Invariant A lane offsets within a packed half-buffer.
  size_t aoff[4];
#pragma unroll
  for (int i = 0; i < 4; ++i)
    aoff[i] = (((size_t)(i * 128 + wloc * 32 + quad)) * 16 + l15) * 8;

  // h output address (constant across steps except slot bit)
  const size_t hoff = ((size_t)((lane >> 4) * 128 + (u0 >> 3))) * 128 +
                      (lane & 15) * 8 + (u0 & 7);

  for (int d = 0; d < kT + kL - 1; ++d) {
    const int t = d - l;
    if (t >= 0 && t < kT) {
      const unsigned short* srcA;
      if (half == 0) {
        srcA = (l == 0) ? (xp + (size_t)t * kABlk)
                        : (hp + ((size_t)((t & 1) * kL + (l - 1))) * kABlk);
      } else {
        srcA = hp + ((size_t)(((t + 1) & 1) * kL + l)) * kABlk;
      }

      f32x4 acc[4][4] = {};
      bf16x8 Aa[4], Ab[4];
#pragma unroll
      for (int i = 0; i < 4; ++i) Aa[i] = *(const bf16x8*)(srcA + aoff[i]);
#pragma unroll
      for (int kc = 0; kc < 8; ++kc) {
        bf16x8* Ac = (kc & 1) ? Ab : Aa;
        bf16x8* An = (kc & 1) ? Aa : Ab;
        if (kc < 7) {
#pragma unroll
          for (int i = 0; i < 4; ++i)
            An[i] = *(const bf16x8*)(srcA + aoff[i] + (size_t)(kc + 1) * 512);
        }
#pragma unroll
        for (int mt = 0; mt < 4; ++mt)
#pragma unroll
          for (int nt = 0; nt < 4; ++nt)
            acc[mt][nt] = __builtin_amdgcn_mfma_f32_16x16x32_bf16(
                Ac[mt], Bw[kc][nt], acc[mt][nt], 0, 0, 0);
      }

      // ---- write per-wave partials (stride 68: ~2-way banks) ----
      {
        float* p = &part[w][0][0];
#pragma unroll
        for (int mt = 0; mt < 4; ++mt)
#pragma unroll
          for (int nt = 0; nt < 4; ++nt)
#pragma unroll
            for (int r = 0; r < 4; ++r)
              p[(mt * 16 + quad * 4 + r) * 68 + nt * 16 + l15] = acc[mt][nt][r];
      }
      __syncthreads();

      // ---- epilogue: thread -> batch m=lane, units u0, u0+1 ----
      {
        f32x4 s0 = bb0, s1 = bb1;
#pragma unroll
        for (int p8 = 0; p8 < 8; ++p8) {
          s0 += *(const f32x4*)&part[p8][lane][8 * w];
          s1 += *(const f32x4*)&part[p8][lane][8 * w + 4];
        }
        float gi0 = sigm_(s0[0]), gf0 = sigm_(s0[1]);
        float gg0 = tanh_(s0[2]), go0 = sigm_(s0[3]);
        float gi1 = sigm_(s1[0]), gf1 = sigm_(s1[1]);
        float gg1 = tanh_(s1[2]), go1 = sigm_(s1[3]);
        float cn0 = gf0 * c0 + gi0 * gg0;
        float cn1 = gf1 * c1 + gi1 * gg1;
        c0 = cn0;
        c1 = cn1;
        unsigned int hv = (unsigned int)f2bf(go0 * tanh_(cn0)) |
                          ((unsigned int)f2bf(go1 * tanh_(cn1)) << 16);
        *(unsigned int*)(hp + ((size_t)((t & 1) * kL + l)) * kABlk + hoff) = hv;
      }
      __syncthreads();  // part[] reused next step
    }
    grid.sync();
  }
}

// Final FC: out[64,512] = h[L-1, t=255] @ W_fc^T + b_fc (h3 in packed layout).
__global__ __launch_bounds__(256) void lstm_fc(const unsigned short* __restrict__ h3,
                                               const float* __restrict__ Wfc,
                                               const float* __restrict__ bfc,
                                               float* __restrict__ out) {
  int gt = blockIdx.x * 256 + threadIdx.x;  // 32768 exact
  int b = gt >> 9, o = gt & 511;
  const unsigned short* hr = h3 + (size_t)(b >> 4) * 16384 + (b & 15) * 8;
  const float* wr = Wfc + (size_t)o * kH;
  float acc = bfc[o];
#pragma unroll 4
  for (int k8 = 0; k8 < 128; ++k8) {
    u16x8 hv = *(const u16x8*)(hr + (size_t)k8 * 128);
    float4 w0 = *(const float4*)(wr + k8 * 8);
    float4 w1 = *(const float4*)(wr + k8 * 8 + 4);
    acc += bf2f(hv[0]) * w0.x + bf2f(hv[1]) * w0.y + bf2f(hv[2]) * w0.z +
           bf2f(hv[3]) * w0.w + bf2f(hv[4]) * w1.x + bf2f(hv[5]) * w1.y +
           bf2f(hv[6]) * w1.z + bf2f(hv[7]) * w1.w;
  }
  out[gt] = acc;
}

extern "C" void kernel_launch(void* const* d_in, const int* in_sizes, int n_in,
                              void* d_out, int out_size, void* d_ws, size_t ws_size,
                              hipStream_t stream) {
  (void)in_sizes; (void)n_in; (void)out_size; (void)ws_size;
  const float* x   = (const float*)d_in[0];
  const float* Wih = (const float*)d_in[1];
  const float* Whh = (const float*)d_in[2];
  const float* bih = (const float*)d_in[3];
  const float* bhh = (const float*)d_in[4];
  const float* Wfc = (const float*)d_in[5];
  const float* bfc = (const float*)d_in[6];
  float* out = (float*)d_out;

  char* ws = (char*)d_ws;
  unsigned short* Wp   = (unsigned short*)(ws + OFF_W);
  float*          bias = (float*)(ws + OFF_BIAS);
  unsigned short* xp   = (unsigned short*)(ws + OFF_XB);
  unsigned short* hpp  = (unsigned short*)(ws + OFF_H);

  prepack_w<<<16384, 256, 0, stream>>>(Wih, Whh, Wp);
  prepack_bias<<<64, 256, 0, stream>>>(bih, bhh, bias);
  prepack_x<<<8192, 256, 0, stream>>>(x, xp);
  hipMemsetAsync(ws + OFF_H, 0, 1048576, stream);  // hp (both slots)

  void* args[4] = {(void*)&Wp, (void*)&bias, (void*)&xp, (void*)&hpp};
  hipLaunchCooperativeKernel((void*)lstm_persist, dim3(256), dim3(512), args, 0,
                             stream);

  // h[layer 3] at t=255 -> slot 1: offset (1*4+3)*kABlk
  lstm_fc<<<128, 256, 0, stream>>>(hpp + (size_t)7 * kABlk, Wfc, bfc, out);
}

// Round 3
// 4867.916 us; speedup vs baseline: 2.8812x; 2.0255x over previous
//
#include <hip/hip_runtime.h>

// ---------------------------------------------------------------------------
// LSTM (L=4, B=64, T=256, H=D=1024, O=512).
// Round 5: (1) weights FORCED into VGPRs via asm keep-alive (R4's pin failed:
// VGPR_Count=128 proves the compiler rematerialized the 128-reg B-tile loads
// inside the loop -> 64 MB/step streamed from L3 at ~1.7 TB/s = 37 us/step).
// (2) grid.sync() replaced by per-(l,t) flag sync (device-scope atomics +
// leader acquire/release fences): layers pipeline, no full-grid barrier, and
// no full-L2-invalidate serialization. WGs run t=0..255 directly.
// Deps per (l,t): flag[l-1][t] (input h), flag[l][t-1] (recurrent h),
// flag[l+1][t-2] (WAR guard on the 2-deep h ring slot). DAG is acyclic;
// steady-state lag of layer l+1 is 1 cell-time so the guard never stalls.
// Packed layout for a [R x K] bf16 operand: [R/16][K/8][R%16][8].
// Gate-interleaved rows: packed row n = gate (n&3) of unit (n>>2).
// ---------------------------------------------------------------------------

typedef short           bf16x8 __attribute__((ext_vector_type(8)));
typedef unsigned short  u16x8  __attribute__((ext_vector_type(8)));
typedef float           f32x4  __attribute__((ext_vector_type(4)));

static constexpr int kB  = 64;
static constexpr int kT  = 256;
static constexpr int kH  = 1024;
static constexpr int kL  = 4;
static constexpr int kNG = 4096;       // 4*H

static constexpr int kABlk = 65536;    // one A half: [4][128][16][8] = 64x1024

// ws layout (bytes)
static constexpr size_t OFF_W    = 0;           // bf16 Wp    67,108,864
static constexpr size_t OFF_BIAS = 67108864;    // f32 bias       65,536
static constexpr size_t OFF_XB   = 67174400;    // bf16 xp    33,554,432
static constexpr size_t OFF_H    = 100728832;   // bf16 hp[2][L][64x1024] 1 MB
static constexpr size_t OFF_FLAG = 101777408;   // int flags[4][256] = 4 KB

static __device__ __forceinline__ unsigned short f2bf(float f) {
  unsigned int u = __float_as_uint(f);
  u += 0x7fffu + ((u >> 16) & 1u);  // RNE
  return (unsigned short)(u >> 16);
}
static __device__ __forceinline__ float bf2f(unsigned short s) {
  return __uint_as_float(((unsigned int)s) << 16);
}
static __device__ __forceinline__ float sigm_(float x) {
  return 1.0f / (1.0f + __expf(-x));
}
static __device__ __forceinline__ float tanh_(float x) {
  return 1.0f - 2.0f / (__expf(2.0f * x) + 1.0f);
}

// Pack weights: Wp[l][r16][k8][l15][8], row n=r16*16+l15 (gate-interleaved),
// source row r=(n&3)*1024+(n>>2); k = k8*8 (<1024 -> Wih, else Whh).
__global__ __launch_bounds__(256) void prepack_w(const float* __restrict__ Wih,
                                                 const float* __restrict__ Whh,
                                                 unsigned short* __restrict__ Wp) {
  unsigned int e8 = blockIdx.x * 256 + threadIdx.x;  // < 4,194,304 (exact)
  const int l15 = e8 & 15;
  const int k8  = (e8 >> 4) & 255;
  const int r16 = (e8 >> 12) & 255;
  const int l   = e8 >> 20;
  const int n   = r16 * 16 + l15;
  const int r   = (n & 3) * 1024 + (n >> 2);
  const int k   = k8 * 8;
  const float* src = (k < 1024)
      ? (Wih + ((size_t)l * kNG + r) * 1024 + k)
      : (Whh + ((size_t)l * kNG + r) * 1024 + (k - 1024));
  float4 f0 = *(const float4*)(src);
  float4 f1 = *(const float4*)(src + 4);
  u16x8 v;
  v[0] = f2bf(f0.x); v[1] = f2bf(f0.y); v[2] = f2bf(f0.z); v[3] = f2bf(f0.w);
  v[4] = f2bf(f1.x); v[5] = f2bf(f1.y); v[6] = f2bf(f1.z); v[7] = f2bf(f1.w);
  *(u16x8*)(Wp + (size_t)e8 * 8) = v;
}

__global__ __launch_bounds__(256) void prepack_bias(const float* __restrict__ bih,
                                                    const float* __restrict__ bhh,
                                                    float* __restrict__ bias) {
  int e = blockIdx.x * 256 + threadIdx.x;  // 16384 exact
  int l = e >> 12, n = e & 4095;
  int r = (n & 3) * 1024 + (n >> 2);
  bias[e] = bih[l * kNG + r] + bhh[l * kNG + r];
}

// Pack x: xp[t][m16][k8][l15][8], batch m=m16*16+l15.
__global__ __launch_bounds__(256) void prepack_x(const float* __restrict__ x,
                                                 unsigned short* __restrict__ xp) {
  unsigned int e8 = blockIdx.x * 256 + threadIdx.x;  // < 2,097,152 (exact)
  const int l15 = e8 & 15;
  const int k8  = (e8 >> 4) & 127;
  const int m16 = (e8 >> 11) & 3;
  const int t   = e8 >> 13;
  const int mm  = m16 * 16 + l15;
  const float* src = x + ((size_t)mm * kT + t) * kH + k8 * 8;
  float4 f0 = *(const float4*)(src);
  float4 f1 = *(const float4*)(src + 4);
  u16x8 v;
  v[0] = f2bf(f0.x); v[1] = f2bf(f0.y); v[2] = f2bf(f0.z); v[3] = f2bf(f0.w);
  v[4] = f2bf(f1.x); v[5] = f2bf(f1.y); v[6] = f2bf(f1.z); v[7] = f2bf(f1.w);
  *(u16x8*)(xp + (size_t)e8 * 8) = v;
}

static __device__ __forceinline__ void spinwait64(int* p) {
  while (__hip_atomic_load(p, __ATOMIC_RELAXED, __HIP_MEMORY_SCOPE_AGENT) < 64)
    __builtin_amdgcn_s_sleep(2);
}

// Persistent kernel, 256 WGs (l = bid>>6, slab = bid&63), 512 thr = 8 waves,
// K-split-8 (waves 0-3 input half, 4-7 recurrent half). Weights, bias, and
// cell state live in VGPRs for all 256 steps; flag-based producer/consumer
// sync between layers (no grid barrier).
__global__ __launch_bounds__(512, 2) void lstm_persist(
    const unsigned short* __restrict__ Wp, const float* __restrict__ bias,
    const unsigned short* __restrict__ xp, unsigned short* __restrict__ hp,
    int* __restrict__ flags) {
  const int l    = blockIdx.x >> 6;
  const int slab = blockIdx.x & 63;
  const int tid  = threadIdx.x;
  const int lane = tid & 63;
  const int w    = tid >> 6;       // 0..7: K range [w*256, w*256+256)
  const int quad = lane >> 4;
  const int l15  = lane & 15;
  const int half = w >> 2;         // 0: input half, 1: recurrent half
  const int wloc = w & 3;

  __shared__ float part[8][64][68];  // 139,264 B (1 WG/CU)

  // ---- one-time: this wave's 64x256 B tile -> 32 frags = 128 VGPRs ----
  bf16x8 Bw[8][4];  // [kc][nt]
#pragma unroll
  for (int i = 0; i < 4; ++i) {
    const unsigned short* pb =
        Wp + ((((size_t)(l * 256 + slab * 4 + i)) * 256 +
               (size_t)(w * 32 + quad)) * 16 + l15) * 8;
#pragma unroll
    for (int kc = 0; kc < 8; ++kc)
      Bw[kc][i] = *(const bf16x8*)(pb + (size_t)kc * 512);
  }
  // Sever each fragment from its load so the compiler CANNOT rematerialize
  // the loads inside the t-loop (R4 failure mode). Forces 128 live VGPRs.
#pragma unroll
  for (int kc = 0; kc < 8; ++kc)
#pragma unroll
    for (int i = 0; i < 4; ++i)
      asm volatile("" : "+v"(Bw[kc][i]));

  // ---- one-time: bias for this thread's 2 units (u0 = slab*16+2w, +1) ----
  const int u0 = slab * 16 + 2 * w;
  f32x4 bb0, bb1;
  {
    const float* bb = bias + (size_t)l * kNG + slab * 64 + 8 * w;
    bb0 = *(const f32x4*)bb;
    bb1 = *(const f32x4*)(bb + 4);
  }
  float c0 = 0.0f, c1 = 0.0f;  // cell state in regs (mapping constant)

  // Invariant A lane offsets (elements) within a packed half-buffer.
  int aoff[4];
#pragma unroll
  for (int i = 0; i < 4; ++i)
    aoff[i] = ((i * 128 + wloc * 32 + quad) * 16 + l15) * 8;

  // h output offset (elements; slot bit varies per step)
  const int hoff =
      ((lane >> 4) * 128 + (u0 >> 3)) * 128 + (lane & 15) * 8 + (u0 & 7);

  for (int t = 0; t < kT; ++t) {
    // ---- consumer waits (leader) + acquire, then block barrier ----
    if (tid == 0) {
      if (l > 0) spinwait64(flags + (l - 1) * 256 + t);      // input h ready
      if (t > 0) spinwait64(flags + l * 256 + (t - 1));      // recurrent ready
      if (l < 3 && t >= 2) spinwait64(flags + (l + 1) * 256 + (t - 2));  // WAR
      __builtin_amdgcn_fence(__ATOMIC_ACQUIRE, "agent");
    }
    __syncthreads();

    const unsigned short* srcA;
    if (half == 0) {
      srcA = (l == 0) ? (xp + (size_t)t * kABlk)
                      : (hp + (size_t)((t & 1) * kL + (l - 1)) * kABlk);
    } else {
      srcA = hp + (size_t)(((t + 1) & 1) * kL + l) * kABlk;
    }

    f32x4 acc[4][4] = {};
    bf16x8 Aa[4], Ab[4];
#pragma unroll
    for (int i = 0; i < 4; ++i) Aa[i] = *(const bf16x8*)(srcA + aoff[i]);
#pragma unroll
    for (int kc = 0; kc < 8; ++kc) {
      bf16x8* Ac = (kc & 1) ? Ab : Aa;
      bf16x8* An = (kc & 1) ? Aa : Ab;
      if (kc < 7) {
#pragma unroll
        for (int i = 0; i < 4; ++i)
          An[i] = *(const bf16x8*)(srcA + aoff[i] + (kc + 1) * 512);
      }
#pragma unroll
      for (int mt = 0; mt < 4; ++mt)
#pragma unroll
        for (int nt = 0; nt < 4; ++nt)
          acc[mt][nt] = __builtin_amdgcn_mfma_f32_16x16x32_bf16(
              Ac[mt], Bw[kc][nt], acc[mt][nt], 0, 0, 0);
    }

    // ---- K-split-8 reduction through LDS (stride 68: ~2-way banks) ----
    {
      float* p = &part[w][0][0];
#pragma unroll
      for (int mt = 0; mt < 4; ++mt)
#pragma unroll
        for (int nt = 0; nt < 4; ++nt)
#pragma unroll
          for (int r = 0; r < 4; ++r)
            p[(mt * 16 + quad * 4 + r) * 68 + nt * 16 + l15] = acc[mt][nt][r];
    }
    __syncthreads();

    // ---- epilogue: thread -> batch m=lane, units u0, u0+1 ----
    {
      f32x4 s0 = bb0, s1 = bb1;
#pragma unroll
      for (int p8 = 0; p8 < 8; ++p8) {
        s0 += *(const f32x4*)&part[p8][lane][8 * w];
        s1 += *(const f32x4*)&part[p8][lane][8 * w + 4];
      }
      float gi0 = sigm_(s0[0]), gf0 = sigm_(s0[1]);
      float gg0 = tanh_(s0[2]), go0 = sigm_(s0[3]);
      float gi1 = sigm_(s1[0]), gf1 = sigm_(s1[1]);
      float gg1 = tanh_(s1[2]), go1 = sigm_(s1[3]);
      float cn0 = gf0 * c0 + gi0 * gg0;
      float cn1 = gf1 * c1 + gi1 * gg1;
      c0 = cn0;
      c1 = cn1;
      unsigned int hv = (unsigned int)f2bf(go0 * tanh_(cn0)) |
                        ((unsigned int)f2bf(go1 * tanh_(cn1)) << 16);
      *(unsigned int*)(hp + (size_t)((t & 1) * kL + l) * kABlk + hoff) = hv;
    }
    __syncthreads();  // all h stores issued (vmcnt drained) + part reusable

    // ---- producer publish (leader): release then count up ----
    if (tid == 0) {
      __builtin_amdgcn_fence(__ATOMIC_RELEASE, "agent");
      __hip_atomic_fetch_add(flags + l * 256 + t, 1, __ATOMIC_RELAXED,
                             __HIP_MEMORY_SCOPE_AGENT);
    }
  }
}

// Final FC: out[64,512] = h[L-1, t=255] @ W_fc^T + b_fc (h3 in packed layout).
__global__ __launch_bounds__(256) void lstm_fc(const unsigned short* __restrict__ h3,
                                               const float* __restrict__ Wfc,
                                               const float* __restrict__ bfc,
                                               float* __restrict__ out) {
  int gt = blockIdx.x * 256 + threadIdx.x;  // 32768 exact
  int b = gt >> 9, o = gt & 511;
  const unsigned short* hr = h3 + (size_t)(b >> 4) * 16384 + (b & 15) * 8;
  const float* wr = Wfc + (size_t)o * kH;
  float acc = bfc[o];
#pragma unroll 4
  for (int k8 = 0; k8 < 128; ++k8) {
    u16x8 hv = *(const u16x8*)(hr + (size_t)k8 * 128);
    float4 w0 = *(const float4*)(wr + k8 * 8);
    float4 w1 = *(const float4*)(wr + k8 * 8 + 4);
    acc += bf2f(hv[0]) * w0.x + bf2f(hv[1]) * w0.y + bf2f(hv[2]) * w0.z +
           bf2f(hv[3]) * w0.w + bf2f(hv[4]) * w1.x + bf2f(hv[5]) * w1.y +
           bf2f(hv[6]) * w1.z + bf2f(hv[7]) * w1.w;
  }
  out[gt] = acc;
}

extern "C" void kernel_launch(void* const* d_in, const int* in_sizes, int n_in,
                              void* d_out, int out_size, void* d_ws, size_t ws_size,
                              hipStream_t stream) {
  (void)in_sizes; (void)n_in; (void)out_size; (void)ws_size;
  const float* x   = (const float*)d_in[0];
  const float* Wih = (const float*)d_in[1];
  const float* Whh = (const float*)d_in[2];
  const float* bih = (const float*)d_in[3];
  const float* bhh = (const float*)d_in[4];
  const float* Wfc = (const float*)d_in[5];
  const float* bfc = (const float*)d_in[6];
  float* out = (float*)d_out;

  char* ws = (char*)d_ws;
  unsigned short* Wp   = (unsigned short*)(ws + OFF_W);
  float*          bias = (float*)(ws + OFF_BIAS);
  unsigned short* xp   = (unsigned short*)(ws + OFF_XB);
  unsigned short* hpp  = (unsigned short*)(ws + OFF_H);
  int*            flg  = (int*)(ws + OFF_FLAG);

  prepack_w<<<16384, 256, 0, stream>>>(Wih, Whh, Wp);
  prepack_bias<<<64, 256, 0, stream>>>(bih, bhh, bias);
  prepack_x<<<8192, 256, 0, stream>>>(x, xp);
  hipMemsetAsync(ws + OFF_H, 0, 1048576 + 4096, stream);  // hp ring + flags

  void* args[5] = {(void*)&Wp, (void*)&bias, (void*)&xp, (void*)&hpp, (void*)&flg};
  hipLaunchCooperativeKernel((void*)lstm_persist, dim3(256), dim3(512), args, 0,
                             stream);

  // h[layer 3] at t=255 -> slot 1: offset (1*4+3)*kABlk
  lstm_fc<<<128, 256, 0, stream>>>(hpp + (size_t)7 * kABlk, Wfc, bfc, out);
}